// Round 1
// baseline (392.590 us; speedup 1.0000x reference)
//
#include <hip/hip_runtime.h>
#include <math.h>

// RAMAC: x (16,1024,64,64) f32 -> out (16,1024) f32
// v[b,c] = sum over 15 macs (full image counted twice):
//   mac_r = vt_r[b,c] / (||vt_r[b,:]||2 + eps) * wgt_r
//   vt_r[b,c] = max over region r of x[b,c,:,:]
//   wgt_r = count(tt in region over ALL b) / area_r, zeroed if <= 1/3
//   tt[b,h,w] = (sum_c x[b,c,h,w]) - mean > 0, mean global over (b,h,w)
//
// 14 distinct regions (H=W=64, L=3):
//   r0 : rows[0,64) x cols[0,64)            (weight x2, area 4096)
//   r1-4 : {[0,42),[22,64)}^2               (area 1764)
//   r5-13: {[0,32),[16,48),[32,64)}^2       (area 1024)

#define NB 16
#define NC 1024
#define HW 4096
#define NF4 1024          // float4 per image
#define G 16              // channels per block in k1
#define NCHUNK (NC / G)   // 64

// ---------------- DPP wave-64 max reduction (result valid in lane 63) ------
template <int ctrl, int rm, int bm>
__device__ __forceinline__ float maxdpp(float x) {
  int xi = __float_as_int(x);
  int yi = __builtin_amdgcn_update_dpp(xi, xi, ctrl, rm, bm, false);
  return fmaxf(x, __int_as_float(yi));
}
__device__ __forceinline__ float wave_max64(float x) {
  x = maxdpp<0x111, 0xf, 0xf>(x);  // row_shr:1
  x = maxdpp<0x112, 0xf, 0xf>(x);  // row_shr:2
  x = maxdpp<0x114, 0xf, 0xe>(x);  // row_shr:4
  x = maxdpp<0x118, 0xf, 0xc>(x);  // row_shr:8
  x = maxdpp<0x142, 0xa, 0xf>(x);  // row_bcast:15
  x = maxdpp<0x143, 0x8, 0xf>(x);  // row_bcast:31
  return x;                        // lane 63 holds wave max
}

// ---------------- Kernel 1: single pass over x --------------------------
// grid (NCHUNK, NB), block 256. Thread t owns float4 indices {t+256k, k=0..3}:
//   fb = t&15  (float4-within-row -> cols 4fb..4fb+3), row_k = (t>>4)+16k.
// Produces: per-wave region-max partials vtp[r][b][c][wave], and channel-sum
// chunk partials spart[(chunk*16+b)*1024 + f4].
__global__ __launch_bounds__(256) void k1_main(
    const float4* __restrict__ x, float* __restrict__ vtp,
    float4* __restrict__ spart4, float* __restrict__ total,
    int* __restrict__ cnt) {
  const int t = threadIdx.x;
  const int chunk = blockIdx.x;
  const int b = blockIdx.y;
  if (chunk == 0 && b == 0) {  // zero accumulators consumed by k2/k3
    if (t == 0) *total = 0.f;
    if (t < 14) cnt[t] = 0;
  }
  const int fb = t & 15;
  const int r0 = t >> 4;
  const int w = t >> 6;
  const float NEG = -INFINITY;
  // thread-constant column-interval masks
  const bool cAf = (fb <= 9), cAp = (fb == 10);   // [0,42): full / cols 40,41
  const bool cBf = (fb >= 6), cBp = (fb == 5);    // [22,64): full / cols 22,23
  const bool cCm = (fb < 8);                      // [0,32)
  const bool cDm = (fb >= 4) && (fb < 12);        // [16,48)
  const bool cEm = (fb >= 8);                     // [32,64)
  // row-interval edge conditions (others are static per k)
  const bool rAk2 = (r0 < 10);  // k=2 rows 32..47 in [0,42)
  const bool rBk1 = (r0 >= 6);  // k=1 rows 16..31 in [22,64)

  float4 sa0 = {0, 0, 0, 0}, sa1 = {0, 0, 0, 0}, sa2 = {0, 0, 0, 0},
         sa3 = {0, 0, 0, 0};
  const float4* img = x + (((size_t)(b * NC + chunk * G)) << 10);

  for (int ci = 0; ci < G; ++ci) {
    const float4* p = img + (((size_t)ci) << 10);
    float4 v0 = p[t], v1 = p[t + 256], v2 = p[t + 512], v3 = p[t + 768];
    sa0.x += v0.x; sa0.y += v0.y; sa0.z += v0.z; sa0.w += v0.w;
    sa1.x += v1.x; sa1.y += v1.y; sa1.z += v1.z; sa1.w += v1.w;
    sa2.x += v2.x; sa2.y += v2.y; sa2.z += v2.z; sa2.w += v2.w;
    sa3.x += v3.x; sa3.y += v3.y; sa3.z += v3.z; sa3.w += v3.w;

    float m0 = fmaxf(fmaxf(v0.x, v0.y), fmaxf(v0.z, v0.w));
    float m1 = fmaxf(fmaxf(v1.x, v1.y), fmaxf(v1.z, v1.w));
    float m2 = fmaxf(fmaxf(v2.x, v2.y), fmaxf(v2.z, v2.w));
    float m3 = fmaxf(fmaxf(v3.x, v3.y), fmaxf(v3.z, v3.w));
    // boundary partials: pA = cols 40,41 (fb==10: .x,.y); pB = cols 22,23 (fb==5: .z,.w)
    float pA0 = fmaxf(v0.x, v0.y), pA1 = fmaxf(v1.x, v1.y);
    float pA2 = fmaxf(v2.x, v2.y), pA3 = fmaxf(v3.x, v3.y);
    float pB0 = fmaxf(v0.z, v0.w), pB1 = fmaxf(v1.z, v1.w);
    float pB2 = fmaxf(v2.z, v2.w), pB3 = fmaxf(v3.z, v3.w);

    float cA0 = cAf ? m0 : (cAp ? pA0 : NEG);
    float cA1 = cAf ? m1 : (cAp ? pA1 : NEG);
    float cA2 = cAf ? m2 : (cAp ? pA2 : NEG);
    float cA3 = cAf ? m3 : (cAp ? pA3 : NEG);
    float cB0 = cBf ? m0 : (cBp ? pB0 : NEG);
    float cB1 = cBf ? m1 : (cBp ? pB1 : NEG);
    float cB2 = cBf ? m2 : (cBp ? pB2 : NEG);
    float cB3 = cBf ? m3 : (cBp ? pB3 : NEG);
    float cC0 = cCm ? m0 : NEG, cC1 = cCm ? m1 : NEG;
    float cC2 = cCm ? m2 : NEG, cC3 = cCm ? m3 : NEG;
    float cD0 = cDm ? m0 : NEG, cD1 = cDm ? m1 : NEG;
    float cD2 = cDm ? m2 : NEG, cD3 = cDm ? m3 : NEG;
    float cE0 = cEm ? m0 : NEG, cE1 = cEm ? m1 : NEG;
    float cE2 = cEm ? m2 : NEG, cE3 = cEm ? m3 : NEG;

    // fold k (rows) into 14 region partials.
    // k=0 rows[0,16): A,C   k=1 rows[16,32): A,C,D,(B if r0>=6)
    // k=2 rows[32,48): B,D,E,(A if r0<10)   k=3 rows[48,64): B,E
    float g0 = fmaxf(fmaxf(m0, m1), fmaxf(m2, m3));
    float g1 = fmaxf(fmaxf(cA0, cA1), rAk2 ? cA2 : NEG);
    float g2 = fmaxf(fmaxf(cB0, cB1), rAk2 ? cB2 : NEG);
    float g3 = fmaxf(fmaxf(cA2, cA3), rBk1 ? cA1 : NEG);
    float g4 = fmaxf(fmaxf(cB2, cB3), rBk1 ? cB1 : NEG);
    float g5 = fmaxf(cC0, cC1), g6 = fmaxf(cD0, cD1), g7 = fmaxf(cE0, cE1);
    float g8 = fmaxf(cC1, cC2), g9 = fmaxf(cD1, cD2), g10 = fmaxf(cE1, cE2);
    float g11 = fmaxf(cC2, cC3), g12 = fmaxf(cD2, cD3), g13 = fmaxf(cE2, cE3);

    g0 = wave_max64(g0);   g1 = wave_max64(g1);   g2 = wave_max64(g2);
    g3 = wave_max64(g3);   g4 = wave_max64(g4);   g5 = wave_max64(g5);
    g6 = wave_max64(g6);   g7 = wave_max64(g7);   g8 = wave_max64(g8);
    g9 = wave_max64(g9);   g10 = wave_max64(g10); g11 = wave_max64(g11);
    g12 = wave_max64(g12); g13 = wave_max64(g13);

    if ((t & 63) == 63) {
      const int c = chunk * G + ci;
      const int base = ((b << 10) + c) * 4 + w;  // region stride 65536 floats
      vtp[base]            = g0;  vtp[base + 1 * 65536] = g1;
      vtp[base + 2 * 65536] = g2; vtp[base + 3 * 65536] = g3;
      vtp[base + 4 * 65536] = g4; vtp[base + 5 * 65536] = g5;
      vtp[base + 6 * 65536] = g6; vtp[base + 7 * 65536] = g7;
      vtp[base + 8 * 65536] = g8; vtp[base + 9 * 65536] = g9;
      vtp[base + 10 * 65536] = g10; vtp[base + 11 * 65536] = g11;
      vtp[base + 12 * 65536] = g12; vtp[base + 13 * 65536] = g13;
    }
  }
  const int sb = ((chunk * NB + b) << 10);
  spart4[sb + t] = sa0;
  spart4[sb + t + 256] = sa1;
  spart4[sb + t + 512] = sa2;
  spart4[sb + t + 768] = sa3;
}

// ---------------- Kernel 2: s = sum over chunks; total = sum(s) ----------
__global__ __launch_bounds__(256) void k2_s(const float4* __restrict__ spart4,
                                            float4* __restrict__ s4,
                                            float* __restrict__ total) {
  const int id = blockIdx.x * 256 + threadIdx.x;  // 0..16383 (b*1024 + f4)
  float4 acc = {0, 0, 0, 0};
  for (int ch = 0; ch < NCHUNK; ++ch) {
    float4 v = spart4[(ch << 14) + id];
    acc.x += v.x; acc.y += v.y; acc.z += v.z; acc.w += v.w;
  }
  s4[id] = acc;
  float ts = (acc.x + acc.y) + (acc.z + acc.w);
  for (int off = 1; off < 64; off <<= 1) ts += __shfl_xor(ts, off);
  if ((threadIdx.x & 63) == 0) atomicAdd(total, ts);
}

// ---------------- Kernel 3: region counts of tt -------------------------
__global__ __launch_bounds__(256) void k3_cnt(const float* __restrict__ s,
                                              const float* __restrict__ total,
                                              int* __restrict__ cnt) {
  const int b = blockIdx.x;
  const int t = threadIdx.x;
  const float mean = *total * (1.0f / 65536.0f);
  int loc[14];
#pragma unroll
  for (int r = 0; r < 14; ++r) loc[r] = 0;
#pragma unroll
  for (int k = 0; k < 16; ++k) {
    const int p = t + 256 * k;
    const int row = p >> 6, col = p & 63;
    const bool tt = s[(b << 12) + p] > mean;
    if (tt) {
      const bool rA = row < 42, rB = row >= 22, rC = row < 32;
      const bool rD = (row >= 16) && (row < 48), rE = row >= 32;
      const bool cA = col < 42, cB = col >= 22, cC = col < 32;
      const bool cD = (col >= 16) && (col < 48), cE = col >= 32;
      loc[0]++;
      loc[1] += rA && cA;  loc[2] += rA && cB;
      loc[3] += rB && cA;  loc[4] += rB && cB;
      loc[5] += rC && cC;  loc[6] += rC && cD;  loc[7] += rC && cE;
      loc[8] += rD && cC;  loc[9] += rD && cD;  loc[10] += rD && cE;
      loc[11] += rE && cC; loc[12] += rE && cD; loc[13] += rE && cE;
    }
  }
#pragma unroll
  for (int r = 0; r < 14; ++r) {
    int v = loc[r];
    for (int off = 1; off < 64; off <<= 1) v += __shfl_xor(v, off);
    if ((t & 63) == 0) atomicAdd(&cnt[r], v);
  }
}

// ---------------- Kernel 4: vt = max of 4 wave partials; nrm ------------
__global__ __launch_bounds__(256) void k4_vt(const float4* __restrict__ vtp4,
                                             float* __restrict__ vt,
                                             float* __restrict__ nrm) {
  const int rb = blockIdx.x;  // r*16 + b, 0..223
  const int t = threadIdx.x;
  float acc = 0.f;
#pragma unroll
  for (int k = 0; k < 4; ++k) {
    const int c = t + 256 * k;
    float4 v = vtp4[(rb << 10) + c];
    float m = fmaxf(fmaxf(v.x, v.y), fmaxf(v.z, v.w));
    vt[(rb << 10) + c] = m;
    acc += m * m;
  }
  for (int off = 1; off < 64; off <<= 1) acc += __shfl_xor(acc, off);
  __shared__ float red[4];
  if ((t & 63) == 0) red[t >> 6] = acc;
  __syncthreads();
  if (t == 0) nrm[rb] = sqrtf(red[0] + red[1] + red[2] + red[3]);
}

// ---------------- Kernel 5: epilogue ------------------------------------
__global__ __launch_bounds__(256) void k5_out(const float* __restrict__ vt,
                                              const float* __restrict__ nrm,
                                              const int* __restrict__ cnt,
                                              float* __restrict__ out) {
  const int id = blockIdx.x * 256 + threadIdx.x;  // b*1024 + c
  const int b = id >> 10;
  float acc = 0.f;
#pragma unroll
  for (int r = 0; r < 14; ++r) {
    const float area = (r == 0) ? 4096.f : ((r <= 4) ? 1764.f : 1024.f);
    float wgt = (float)cnt[r] / area;
    if (wgt <= (1.0f / 3.0f)) wgt = 0.f;
    const float mult = (r == 0) ? 2.f : 1.f;
    acc += mult * wgt * vt[r * 16384 + id] / (nrm[r * 16 + b] + 1e-6f);
  }
  out[id] = acc;
}

extern "C" void kernel_launch(void* const* d_in, const int* in_sizes, int n_in,
                              void* d_out, int out_size, void* d_ws,
                              size_t ws_size, hipStream_t stream) {
  const float* x = (const float*)d_in[0];
  float* out = (float*)d_out;

  // workspace layout (floats)
  float* ws = (float*)d_ws;
  float* vtp = ws;                       // 14*16*1024*4   = 917504
  float* spart = vtp + 917504;           // 64*16*4096     = 4194304
  float* s = spart + 4194304;            // 65536
  float* vt = s + 65536;                 // 14*16*1024     = 229376
  float* nrm = vt + 229376;              // 224
  float* total = nrm + 224;              // 1
  int* cnt = (int*)(total + 1);          // 14
  // total ~21.7 MB

  k1_main<<<dim3(NCHUNK, NB), 256, 0, stream>>>(
      (const float4*)x, vtp, (float4*)spart, total, cnt);
  k2_s<<<64, 256, 0, stream>>>((const float4*)spart, (float4*)s, total);
  k3_cnt<<<NB, 256, 0, stream>>>(s, total, cnt);
  k4_vt<<<224, 256, 0, stream>>>((const float4*)vtp, vt, nrm);
  k5_out<<<64, 256, 0, stream>>>(vt, nrm, cnt, out);
}

// Round 2
// 389.964 us; speedup vs baseline: 1.0067x; 1.0067x over previous
//
#include <hip/hip_runtime.h>
#include <math.h>

// RAMAC: x (16,1024,64,64) f32 -> out (16,1024) f32
// v[b,c] = sum over 15 macs (full image counted twice):
//   mac_r = vt_r[b,c] / (||vt_r[b,:]||2 + eps) * wgt_r
//   vt_r[b,c] = max over region r of x[b,c,:,:]
//   wgt_r = count(tt in region over ALL b) / area_r, zeroed if <= 1/3
//   tt[b,h,w] = (sum_c x[b,c,h,w]) - mean > 0, mean global over (b,h,w)
//
// 14 distinct regions (H=W=64, L=3):
//   r0 : rows[0,64) x cols[0,64)            (weight x2, area 4096)
//   r1-4 : {[0,42),[22,64)}^2               (area 1764)
//   r5-13: {[0,32),[16,48),[32,64)}^2       (area 1024)

#define NB 16
#define NC 1024
#define G 16              // channels per block in k1
#define NCHUNK (NC / G)   // 64

// ---------------- DPP wave-64 max reduction (result valid in lane 63) ------
template <int ctrl, int rm, int bm>
__device__ __forceinline__ float maxdpp(float x) {
  int xi = __float_as_int(x);
  int yi = __builtin_amdgcn_update_dpp(xi, xi, ctrl, rm, bm, false);
  return fmaxf(x, __int_as_float(yi));
}
__device__ __forceinline__ float wave_max64(float x) {
  x = maxdpp<0x111, 0xf, 0xf>(x);  // row_shr:1
  x = maxdpp<0x112, 0xf, 0xf>(x);  // row_shr:2
  x = maxdpp<0x114, 0xf, 0xe>(x);  // row_shr:4
  x = maxdpp<0x118, 0xf, 0xc>(x);  // row_shr:8
  x = maxdpp<0x142, 0xa, 0xf>(x);  // row_bcast:15
  x = maxdpp<0x143, 0x8, 0xf>(x);  // row_bcast:31
  return x;                        // lane 63 holds wave max
}

// ---------------- Kernel 1: single pass over x --------------------------
// grid (NCHUNK, NB), block 256. Thread t owns float4 indices {t+256k, k=0..3}:
//   fb = t&15 (cols 4fb..4fb+3), row_k = (t>>4)+16k.
// Region maxes staged per-channel in LDS, written once per block as float4.
__global__ __launch_bounds__(256) void k1_main(
    const float4* __restrict__ x, float4* __restrict__ vtp4,
    float4* __restrict__ spart4, float* __restrict__ total,
    int* __restrict__ cnt) {
  const int t = threadIdx.x;
  const int chunk = blockIdx.x;
  const int b = blockIdx.y;
  if (chunk == 0 && b == 0) {  // zero accumulators consumed by k2/k3
    if (t == 0) *total = 0.f;
    if (t < 14) cnt[t] = 0;
  }
  const int fb = t & 15;
  const int r0t = t >> 4;
  const int w = t >> 6;
  const float NEG = -INFINITY;
  // thread-constant column-interval masks
  const bool cAf = (fb <= 9), cAp = (fb == 10);   // [0,42): full / cols 40,41
  const bool cBf = (fb >= 6), cBp = (fb == 5);    // [22,64): full / cols 22,23
  const bool cCm = (fb < 8);                      // [0,32)
  const bool cDm = (fb >= 4) && (fb < 12);        // [16,48)
  const bool cEm = (fb >= 8);                     // [32,64)
  // row-interval edge conditions
  const bool rAk2 = (r0t < 10);  // k=2 rows 32..47 in [0,42)
  const bool rBk1 = (r0t >= 6);  // k=1 rows 16..31 in [22,64)

  __shared__ float4 sm4[14][G];  // [r][ci] holds w=0..3 partials

  float4 sa0 = {0, 0, 0, 0}, sa1 = {0, 0, 0, 0}, sa2 = {0, 0, 0, 0},
         sa3 = {0, 0, 0, 0};
  const float4* img = x + (((size_t)(b * NC + chunk * G)) << 10);

  for (int ci = 0; ci < G; ++ci) {
    const float4* p = img + (((size_t)ci) << 10);
    float4 v0 = p[t], v1 = p[t + 256], v2 = p[t + 512], v3 = p[t + 768];
    sa0.x += v0.x; sa0.y += v0.y; sa0.z += v0.z; sa0.w += v0.w;
    sa1.x += v1.x; sa1.y += v1.y; sa1.z += v1.z; sa1.w += v1.w;
    sa2.x += v2.x; sa2.y += v2.y; sa2.z += v2.z; sa2.w += v2.w;
    sa3.x += v3.x; sa3.y += v3.y; sa3.z += v3.z; sa3.w += v3.w;

    // per-row-group float4 maxes
    float m0 = fmaxf(fmaxf(v0.x, v0.y), fmaxf(v0.z, v0.w));
    float m1 = fmaxf(fmaxf(v1.x, v1.y), fmaxf(v1.z, v1.w));
    float m2 = fmaxf(fmaxf(v2.x, v2.y), fmaxf(v2.z, v2.w));
    float m3 = fmaxf(fmaxf(v3.x, v3.y), fmaxf(v3.z, v3.w));
    // boundary partials: pA = cols 40,41 (fb==10: .x,.y); pB = cols 22,23 (fb==5: .z,.w)
    float pA0 = fmaxf(v0.x, v0.y), pA1 = fmaxf(v1.x, v1.y);
    float pA2 = fmaxf(v2.x, v2.y), pA3 = fmaxf(v3.x, v3.y);
    float pB0 = fmaxf(v0.z, v0.w), pB1 = fmaxf(v1.z, v1.w);
    float pB2 = fmaxf(v2.z, v2.w), pB3 = fmaxf(v3.z, v3.w);

    // shared row folds (rows A=[0,42): k0,k1,(k2 if r0<10); B=[22,64): k2,k3,(k1 if r0>=6);
    //                   C=k0,k1; D=k1,k2; E=k2,k3)
    float m01 = fmaxf(m0, m1), m12 = fmaxf(m1, m2), m23 = fmaxf(m2, m3);
    float MAm = fmaxf(m01, rAk2 ? m2 : NEG);
    float MBm = fmaxf(m23, rBk1 ? m1 : NEG);
    float MApA = fmaxf(fmaxf(pA0, pA1), rAk2 ? pA2 : NEG);
    float MApB = fmaxf(fmaxf(pB0, pB1), rAk2 ? pB2 : NEG);
    float MBpA = fmaxf(fmaxf(pA2, pA3), rBk1 ? pA1 : NEG);
    float MBpB = fmaxf(fmaxf(pB2, pB3), rBk1 ? pB1 : NEG);

    float g0 = fmaxf(m01, m23);
    float g1 = cAf ? MAm : (cAp ? MApA : NEG);
    float g2 = cBf ? MAm : (cBp ? MApB : NEG);
    float g3 = cAf ? MBm : (cAp ? MBpA : NEG);
    float g4 = cBf ? MBm : (cBp ? MBpB : NEG);
    float g5 = cCm ? m01 : NEG, g6 = cDm ? m01 : NEG, g7 = cEm ? m01 : NEG;
    float g8 = cCm ? m12 : NEG, g9 = cDm ? m12 : NEG, g10 = cEm ? m12 : NEG;
    float g11 = cCm ? m23 : NEG, g12 = cDm ? m23 : NEG, g13 = cEm ? m23 : NEG;

    g0 = wave_max64(g0);   g1 = wave_max64(g1);   g2 = wave_max64(g2);
    g3 = wave_max64(g3);   g4 = wave_max64(g4);   g5 = wave_max64(g5);
    g6 = wave_max64(g6);   g7 = wave_max64(g7);   g8 = wave_max64(g8);
    g9 = wave_max64(g9);   g10 = wave_max64(g10); g11 = wave_max64(g11);
    g12 = wave_max64(g12); g13 = wave_max64(g13);

    if ((t & 63) == 63) {  // lane 63 of each wave stages 14 partials in LDS
      float* smf = (float*)&sm4[0][0];
      const int o = (ci << 2) + w;     // [r][ci][w], r stride = G*4
      smf[o]               = g0;  smf[o + 1 * (G * 4)] = g1;
      smf[o + 2 * (G * 4)] = g2;  smf[o + 3 * (G * 4)] = g3;
      smf[o + 4 * (G * 4)] = g4;  smf[o + 5 * (G * 4)] = g5;
      smf[o + 6 * (G * 4)] = g6;  smf[o + 7 * (G * 4)] = g7;
      smf[o + 8 * (G * 4)] = g8;  smf[o + 9 * (G * 4)] = g9;
      smf[o + 10 * (G * 4)] = g10; smf[o + 11 * (G * 4)] = g11;
      smf[o + 12 * (G * 4)] = g12; smf[o + 13 * (G * 4)] = g13;
    }
  }
  // channel-sum chunk partials
  const int sb = ((chunk * NB + b) << 10);
  spart4[sb + t] = sa0;
  spart4[sb + t + 256] = sa1;
  spart4[sb + t + 512] = sa2;
  spart4[sb + t + 768] = sa3;

  __syncthreads();
  if (t < 14 * G) {  // one float4 (w=0..3) per (r, ci), coalesced
    const int r = t >> 4, ci = t & 15;
    vtp4[r * (NB * NC) + (b << 10) + (chunk << 4) + ci] = sm4[r][ci];
  }
}

// ---------------- Kernel 2 (merged): s+total | vt+nrm -------------------
// blocks 0..63: s = sum over chunks, total += sum(s)
// blocks 64..287: rb = blk-64: vt = max of 4 wave partials, nrm[rb]
__global__ __launch_bounds__(256) void k2_mid(
    const float4* __restrict__ spart4, float4* __restrict__ s4,
    float* __restrict__ total, const float4* __restrict__ vtp4,
    float* __restrict__ vt, float* __restrict__ nrm) {
  const int blk = blockIdx.x;
  const int t = threadIdx.x;
  __shared__ float red[4];
  if (blk < 64) {
    const int id = blk * 256 + t;  // 0..16383 (b*1024 + f4)
    float4 acc = {0, 0, 0, 0};
    for (int ch = 0; ch < NCHUNK; ++ch) {
      float4 v = spart4[(ch << 14) + id];
      acc.x += v.x; acc.y += v.y; acc.z += v.z; acc.w += v.w;
    }
    s4[id] = acc;
    float ts = (acc.x + acc.y) + (acc.z + acc.w);
    for (int off = 1; off < 64; off <<= 1) ts += __shfl_xor(ts, off);
    if ((t & 63) == 0) atomicAdd(total, ts);
  } else {
    const int rb = blk - 64;  // r*16 + b, 0..223
    float acc = 0.f;
#pragma unroll
    for (int k = 0; k < 4; ++k) {
      const int c = t + 256 * k;
      float4 v = vtp4[(rb << 10) + c];
      float m = fmaxf(fmaxf(v.x, v.y), fmaxf(v.z, v.w));
      vt[(rb << 10) + c] = m;
      acc += m * m;
    }
    for (int off = 1; off < 64; off <<= 1) acc += __shfl_xor(acc, off);
    if ((t & 63) == 0) red[t >> 6] = acc;
    __syncthreads();
    if (t == 0) nrm[rb] = sqrtf(red[0] + red[1] + red[2] + red[3]);
  }
}

// ---------------- Kernel 3: region counts of tt -------------------------
__global__ __launch_bounds__(256) void k3_cnt(const float* __restrict__ s,
                                              const float* __restrict__ total,
                                              int* __restrict__ cnt) {
  const int b = blockIdx.x;
  const int t = threadIdx.x;
  const float mean = *total * (1.0f / 65536.0f);
  int loc[14];
#pragma unroll
  for (int r = 0; r < 14; ++r) loc[r] = 0;
#pragma unroll
  for (int k = 0; k < 16; ++k) {
    const int p = t + 256 * k;
    const int row = p >> 6, col = p & 63;
    const bool tt = s[(b << 12) + p] > mean;
    if (tt) {
      const bool rA = row < 42, rB = row >= 22, rC = row < 32;
      const bool rD = (row >= 16) && (row < 48), rE = row >= 32;
      const bool cA = col < 42, cB = col >= 22, cC = col < 32;
      const bool cD = (col >= 16) && (col < 48), cE = col >= 32;
      loc[0]++;
      loc[1] += rA && cA;  loc[2] += rA && cB;
      loc[3] += rB && cA;  loc[4] += rB && cB;
      loc[5] += rC && cC;  loc[6] += rC && cD;  loc[7] += rC && cE;
      loc[8] += rD && cC;  loc[9] += rD && cD;  loc[10] += rD && cE;
      loc[11] += rE && cC; loc[12] += rE && cD; loc[13] += rE && cE;
    }
  }
#pragma unroll
  for (int r = 0; r < 14; ++r) {
    int v = loc[r];
    for (int off = 1; off < 64; off <<= 1) v += __shfl_xor(v, off);
    if ((t & 63) == 0) atomicAdd(&cnt[r], v);
  }
}

// ---------------- Kernel 4: epilogue ------------------------------------
__global__ __launch_bounds__(256) void k4_out(const float* __restrict__ vt,
                                              const float* __restrict__ nrm,
                                              const int* __restrict__ cnt,
                                              float* __restrict__ out) {
  const int id = blockIdx.x * 256 + threadIdx.x;  // b*1024 + c
  const int b = id >> 10;
  float acc = 0.f;
#pragma unroll
  for (int r = 0; r < 14; ++r) {
    const float area = (r == 0) ? 4096.f : ((r <= 4) ? 1764.f : 1024.f);
    float wgt = (float)cnt[r] / area;
    if (wgt <= (1.0f / 3.0f)) wgt = 0.f;
    const float mult = (r == 0) ? 2.f : 1.f;
    acc += mult * wgt * vt[r * 16384 + id] / (nrm[r * 16 + b] + 1e-6f);
  }
  out[id] = acc;
}

extern "C" void kernel_launch(void* const* d_in, const int* in_sizes, int n_in,
                              void* d_out, int out_size, void* d_ws,
                              size_t ws_size, hipStream_t stream) {
  const float* x = (const float*)d_in[0];
  float* out = (float*)d_out;

  // workspace layout (floats)
  float* ws = (float*)d_ws;
  float* vtp = ws;                       // 14*16*1024*4   = 917504
  float* spart = vtp + 917504;           // 64*16*4096     = 4194304
  float* s = spart + 4194304;            // 65536
  float* vt = s + 65536;                 // 14*16*1024     = 229376
  float* nrm = vt + 229376;              // 224
  float* total = nrm + 224;              // 1
  int* cnt = (int*)(total + 1);          // 14
  // total ~21.7 MB

  k1_main<<<dim3(NCHUNK, NB), 256, 0, stream>>>(
      (const float4*)x, (float4*)vtp, (float4*)spart, total, cnt);
  k2_mid<<<64 + 224, 256, 0, stream>>>((const float4*)spart, (float4*)s, total,
                                       (const float4*)vtp, vt, nrm);
  k3_cnt<<<NB, 256, 0, stream>>>(s, total, cnt);
  k4_out<<<64, 256, 0, stream>>>(vt, nrm, cnt, out);
}

// Round 3
// 385.872 us; speedup vs baseline: 1.0174x; 1.0106x over previous
//
#include <hip/hip_runtime.h>
#include <math.h>

// RAMAC: x (16,1024,64,64) f32 -> out (16,1024) f32
// v[b,c] = sum over 15 macs (full image counted twice):
//   mac_r = vt_r[b,c] / (||vt_r[b,:]||2 + eps) * wgt_r
//   vt_r[b,c] = max over region r of x[b,c,:,:]
//   wgt_r = count(tt in region over ALL b) / area_r, zeroed if <= 1/3
//   tt[b,h,w] = (sum_c x[b,c,h,w]) - mean > 0, mean global over (b,h,w)
//
// 14 distinct regions (H=W=64, L=3):
//   r0 : rows[0,64) x cols[0,64)            (weight x2, area 4096)
//   r1-4 : {[0,42),[22,64)}^2               (area 1764)
//   r5-13: {[0,32),[16,48),[32,64)}^2       (area 1024)

#define NB 16
#define NC 1024
#define G 32              // channels per block in k1
#define NCHUNK (NC / G)   // 32

// ---------------- DPP wave-64 max reduction (result valid in lane 63) ------
template <int ctrl, int rm, int bm>
__device__ __forceinline__ float maxdpp(float x) {
  int xi = __float_as_int(x);
  int yi = __builtin_amdgcn_update_dpp(xi, xi, ctrl, rm, bm, false);
  return fmaxf(x, __int_as_float(yi));
}
__device__ __forceinline__ float wave_max64(float x) {
  x = maxdpp<0x111, 0xf, 0xf>(x);  // row_shr:1
  x = maxdpp<0x112, 0xf, 0xf>(x);  // row_shr:2
  x = maxdpp<0x114, 0xf, 0xe>(x);  // row_shr:4
  x = maxdpp<0x118, 0xf, 0xc>(x);  // row_shr:8
  x = maxdpp<0x142, 0xa, 0xf>(x);  // row_bcast:15
  x = maxdpp<0x143, 0x8, 0xf>(x);  // row_bcast:31
  return x;                        // lane 63 holds wave max
}

// ---------------- Kernel 1: single pass over x --------------------------
// grid (NCHUNK, NB), block 256. Thread t owns float4 indices {t+256k, k=0..3}:
//   fb = t&15 (cols 4fb..4fb+3), row_k = (t>>4)+16k.
// Software-pipelined over channels; region maxes staged per-channel in LDS,
// written once per block as coalesced float4.
__global__ __launch_bounds__(256) void k1_main(
    const float4* __restrict__ x, float4* __restrict__ vtp4,
    float4* __restrict__ spart4, float* __restrict__ total,
    int* __restrict__ cnt) {
  const int t = threadIdx.x;
  const int chunk = blockIdx.x;
  const int b = blockIdx.y;
  if (chunk == 0 && b == 0) {  // zero accumulators consumed by k2/k3
    if (t == 0) *total = 0.f;
    if (t < 14) cnt[t] = 0;
  }
  const int fb = t & 15;
  const int r0t = t >> 4;
  const int w = t >> 6;
  const float NEG = -INFINITY;
  // thread-constant column-interval masks
  const bool cAf = (fb <= 9), cAp = (fb == 10);   // [0,42): full / cols 40,41
  const bool cBf = (fb >= 6), cBp = (fb == 5);    // [22,64): full / cols 22,23
  const bool cCm = (fb < 8);                      // [0,32)
  const bool cDm = (fb >= 4) && (fb < 12);        // [16,48)
  const bool cEm = (fb >= 8);                     // [32,64)
  // row-interval edge conditions
  const bool rAk2 = (r0t < 10);  // k=2 rows 32..47 in [0,42)
  const bool rBk1 = (r0t >= 6);  // k=1 rows 16..31 in [22,64)

  __shared__ float4 sm4[14][G];  // [r][ci] holds w=0..3 partials

  float4 sa0 = {0, 0, 0, 0}, sa1 = {0, 0, 0, 0}, sa2 = {0, 0, 0, 0},
         sa3 = {0, 0, 0, 0};
  const float4* img = x + (((size_t)(b * NC + chunk * G)) << 10);

  auto process = [&](float4 v0, float4 v1, float4 v2, float4 v3, int ci) {
    sa0.x += v0.x; sa0.y += v0.y; sa0.z += v0.z; sa0.w += v0.w;
    sa1.x += v1.x; sa1.y += v1.y; sa1.z += v1.z; sa1.w += v1.w;
    sa2.x += v2.x; sa2.y += v2.y; sa2.z += v2.z; sa2.w += v2.w;
    sa3.x += v3.x; sa3.y += v3.y; sa3.z += v3.z; sa3.w += v3.w;

    // per-row-group float4 maxes
    float m0 = fmaxf(fmaxf(v0.x, v0.y), fmaxf(v0.z, v0.w));
    float m1 = fmaxf(fmaxf(v1.x, v1.y), fmaxf(v1.z, v1.w));
    float m2 = fmaxf(fmaxf(v2.x, v2.y), fmaxf(v2.z, v2.w));
    float m3 = fmaxf(fmaxf(v3.x, v3.y), fmaxf(v3.z, v3.w));
    // boundary partials: pA = cols 40,41 (fb==10: .x,.y); pB = cols 22,23 (.z,.w)
    float pA0 = fmaxf(v0.x, v0.y), pA1 = fmaxf(v1.x, v1.y);
    float pA2 = fmaxf(v2.x, v2.y), pA3 = fmaxf(v3.x, v3.y);
    float pB0 = fmaxf(v0.z, v0.w), pB1 = fmaxf(v1.z, v1.w);
    float pB2 = fmaxf(v2.z, v2.w), pB3 = fmaxf(v3.z, v3.w);

    // shared row folds (A=[0,42): k0,k1,(k2 if r0<10); B=[22,64): k2,k3,(k1 if r0>=6))
    float m01 = fmaxf(m0, m1), m12 = fmaxf(m1, m2), m23 = fmaxf(m2, m3);
    float MAm = fmaxf(m01, rAk2 ? m2 : NEG);
    float MBm = fmaxf(m23, rBk1 ? m1 : NEG);
    float MApA = fmaxf(fmaxf(pA0, pA1), rAk2 ? pA2 : NEG);
    float MApB = fmaxf(fmaxf(pB0, pB1), rAk2 ? pB2 : NEG);
    float MBpA = fmaxf(fmaxf(pA2, pA3), rBk1 ? pA1 : NEG);
    float MBpB = fmaxf(fmaxf(pB2, pB3), rBk1 ? pB1 : NEG);

    float g0 = fmaxf(m01, m23);
    float g1 = cAf ? MAm : (cAp ? MApA : NEG);
    float g2 = cBf ? MAm : (cBp ? MApB : NEG);
    float g3 = cAf ? MBm : (cAp ? MBpA : NEG);
    float g4 = cBf ? MBm : (cBp ? MBpB : NEG);
    float g5 = cCm ? m01 : NEG, g6 = cDm ? m01 : NEG, g7 = cEm ? m01 : NEG;
    float g8 = cCm ? m12 : NEG, g9 = cDm ? m12 : NEG, g10 = cEm ? m12 : NEG;
    float g11 = cCm ? m23 : NEG, g12 = cDm ? m23 : NEG, g13 = cEm ? m23 : NEG;

    g0 = wave_max64(g0);   g1 = wave_max64(g1);   g2 = wave_max64(g2);
    g3 = wave_max64(g3);   g4 = wave_max64(g4);   g5 = wave_max64(g5);
    g6 = wave_max64(g6);   g7 = wave_max64(g7);   g8 = wave_max64(g8);
    g9 = wave_max64(g9);   g10 = wave_max64(g10); g11 = wave_max64(g11);
    g12 = wave_max64(g12); g13 = wave_max64(g13);

    if ((t & 63) == 63) {  // lane 63 of each wave stages 14 partials in LDS
      float* smf = (float*)&sm4[0][0];
      const int o = (ci << 2) + w;     // [r][ci][w], r stride = G*4
      smf[o]               = g0;  smf[o + 1 * (G * 4)] = g1;
      smf[o + 2 * (G * 4)] = g2;  smf[o + 3 * (G * 4)] = g3;
      smf[o + 4 * (G * 4)] = g4;  smf[o + 5 * (G * 4)] = g5;
      smf[o + 6 * (G * 4)] = g6;  smf[o + 7 * (G * 4)] = g7;
      smf[o + 8 * (G * 4)] = g8;  smf[o + 9 * (G * 4)] = g9;
      smf[o + 10 * (G * 4)] = g10; smf[o + 11 * (G * 4)] = g11;
      smf[o + 12 * (G * 4)] = g12; smf[o + 13 * (G * 4)] = g13;
    }
  };

  // software pipeline: prefetch ci+1 before processing ci
  float4 v0 = img[t], v1 = img[t + 256], v2 = img[t + 512], v3 = img[t + 768];
  for (int ci = 0; ci < G - 1; ++ci) {
    const float4* q = img + (((size_t)(ci + 1)) << 10);
    float4 n0 = q[t], n1 = q[t + 256], n2 = q[t + 512], n3 = q[t + 768];
    process(v0, v1, v2, v3, ci);
    v0 = n0; v1 = n1; v2 = n2; v3 = n3;
  }
  process(v0, v1, v2, v3, G - 1);

  // channel-sum chunk partials (partial over this block's G channels)
  const int sb = ((chunk * NB + b) << 10);
  spart4[sb + t] = sa0;
  spart4[sb + t + 256] = sa1;
  spart4[sb + t + 512] = sa2;
  spart4[sb + t + 768] = sa3;

  __syncthreads();
  for (int i = t; i < 14 * G; i += 256) {  // coalesced float4 per (r, ci)
    const int r = i / G, ci = i % G;
    vtp4[r * (NB * NC) + (b << 10) + chunk * G + ci] = sm4[r][ci];
  }
}

// ---------------- Kernel 2 (merged): s+total | vt+nrm -------------------
// blocks 0..63: s = sum over chunks, total += sum(s)
// blocks 64..287: rb = blk-64: vt = max of 4 wave partials, nrm[rb]
__global__ __launch_bounds__(256) void k2_mid(
    const float4* __restrict__ spart4, float4* __restrict__ s4,
    float* __restrict__ total, const float4* __restrict__ vtp4,
    float* __restrict__ vt, float* __restrict__ nrm) {
  const int blk = blockIdx.x;
  const int t = threadIdx.x;
  __shared__ float red[4];
  if (blk < 64) {
    const int id = blk * 256 + t;  // 0..16383 (b*1024 + f4)
    float4 acc = {0, 0, 0, 0};
    for (int ch = 0; ch < NCHUNK; ++ch) {
      float4 v = spart4[(ch << 14) + id];
      acc.x += v.x; acc.y += v.y; acc.z += v.z; acc.w += v.w;
    }
    s4[id] = acc;
    float ts = (acc.x + acc.y) + (acc.z + acc.w);
    for (int off = 1; off < 64; off <<= 1) ts += __shfl_xor(ts, off);
    if ((t & 63) == 0) atomicAdd(total, ts);
  } else {
    const int rb = blk - 64;  // r*16 + b, 0..223
    float acc = 0.f;
#pragma unroll
    for (int k = 0; k < 4; ++k) {
      const int c = t + 256 * k;
      float4 v = vtp4[(rb << 10) + c];
      float m = fmaxf(fmaxf(v.x, v.y), fmaxf(v.z, v.w));
      vt[(rb << 10) + c] = m;
      acc += m * m;
    }
    for (int off = 1; off < 64; off <<= 1) acc += __shfl_xor(acc, off);
    if ((t & 63) == 0) red[t >> 6] = acc;
    __syncthreads();
    if (t == 0) nrm[rb] = sqrtf(red[0] + red[1] + red[2] + red[3]);
  }
}

// ---------------- Kernel 3: region counts of tt -------------------------
__global__ __launch_bounds__(256) void k3_cnt(const float* __restrict__ s,
                                              const float* __restrict__ total,
                                              int* __restrict__ cnt) {
  const int b = blockIdx.x;
  const int t = threadIdx.x;
  const float mean = *total * (1.0f / 65536.0f);
  int loc[14];
#pragma unroll
  for (int r = 0; r < 14; ++r) loc[r] = 0;
#pragma unroll
  for (int k = 0; k < 16; ++k) {
    const int p = t + 256 * k;
    const int row = p >> 6, col = p & 63;
    const bool tt = s[(b << 12) + p] > mean;
    if (tt) {
      const bool rA = row < 42, rB = row >= 22, rC = row < 32;
      const bool rD = (row >= 16) && (row < 48), rE = row >= 32;
      const bool cA = col < 42, cB = col >= 22, cC = col < 32;
      const bool cD = (col >= 16) && (col < 48), cE = col >= 32;
      loc[0]++;
      loc[1] += rA && cA;  loc[2] += rA && cB;
      loc[3] += rB && cA;  loc[4] += rB && cB;
      loc[5] += rC && cC;  loc[6] += rC && cD;  loc[7] += rC && cE;
      loc[8] += rD && cC;  loc[9] += rD && cD;  loc[10] += rD && cE;
      loc[11] += rE && cC; loc[12] += rE && cD; loc[13] += rE && cE;
    }
  }
#pragma unroll
  for (int r = 0; r < 14; ++r) {
    int v = loc[r];
    for (int off = 1; off < 64; off <<= 1) v += __shfl_xor(v, off);
    if ((t & 63) == 0) atomicAdd(&cnt[r], v);
  }
}

// ---------------- Kernel 4: epilogue ------------------------------------
__global__ __launch_bounds__(256) void k4_out(const float* __restrict__ vt,
                                              const float* __restrict__ nrm,
                                              const int* __restrict__ cnt,
                                              float* __restrict__ out) {
  const int id = blockIdx.x * 256 + threadIdx.x;  // b*1024 + c
  const int b = id >> 10;
  float acc = 0.f;
#pragma unroll
  for (int r = 0; r < 14; ++r) {
    const float area = (r == 0) ? 4096.f : ((r <= 4) ? 1764.f : 1024.f);
    float wgt = (float)cnt[r] / area;
    if (wgt <= (1.0f / 3.0f)) wgt = 0.f;
    const float mult = (r == 0) ? 2.f : 1.f;
    acc += mult * wgt * vt[r * 16384 + id] / (nrm[r * 16 + b] + 1e-6f);
  }
  out[id] = acc;
}

extern "C" void kernel_launch(void* const* d_in, const int* in_sizes, int n_in,
                              void* d_out, int out_size, void* d_ws,
                              size_t ws_size, hipStream_t stream) {
  const float* x = (const float*)d_in[0];
  float* out = (float*)d_out;

  // workspace layout (floats)
  float* ws = (float*)d_ws;
  float* vtp = ws;                       // 14*16*1024*4   = 917504
  float* spart = vtp + 917504;           // 32*16*4096     = 2097152
  float* s = spart + 2097152;            // 65536
  float* vt = s + 65536;                 // 14*16*1024     = 229376
  float* nrm = vt + 229376;              // 224
  float* total = nrm + 224;              // 1
  int* cnt = (int*)(total + 1);          // 14
  // total ~13.3 MB

  k1_main<<<dim3(NCHUNK, NB), 256, 0, stream>>>(
      (const float4*)x, (float4*)vtp, (float4*)spart, total, cnt);
  k2_mid<<<64 + 224, 256, 0, stream>>>((const float4*)spart, (float4*)s, total,
                                       (const float4*)vtp, vt, nrm);
  k3_cnt<<<NB, 256, 0, stream>>>(s, total, cnt);
  k4_out<<<64, 256, 0, stream>>>(vt, nrm, cnt, out);
}